// Round 12
// baseline (1125.717 us; speedup 1.0000x reference)
//
#include <hip/hip_runtime.h>

typedef unsigned short u16;
typedef unsigned int u32;
typedef short bf16x8 __attribute__((ext_vector_type(8)));
typedef float f32x4 __attribute__((ext_vector_type(4)));

#define AS1 __attribute__((address_space(1)))
#define AS3 __attribute__((address_space(3)))

__device__ __forceinline__ u16 f2b(float f) {
  u32 u = __float_as_uint(f);
  u += 0x7fffu + ((u >> 16) & 1u);   // round-to-nearest-even
  return (u16)(u >> 16);
}
__device__ __forceinline__ float b2f(u16 s) {
  return __uint_as_float(((u32)s) << 16);
}

__device__ __forceinline__ void gload16(const u16* g, u16* l) {
  __builtin_amdgcn_global_load_lds((const AS1 void*)g, (AS3 void*)l, 16, 0, 0);
}

// ---------------- prologue: cast x -> bf16 AND fill cls rows ----------------
__global__ __launch_bounds__(256) void prep_kernel(const float* __restrict__ x,
                                                   const float* __restrict__ cls,
                                                   u16* __restrict__ xb,
                                                   u16* __restrict__ hb) {
  if (blockIdx.x < 1536) {
    int i = blockIdx.x * 256 + threadIdx.x;
    float4 v = ((const float4*)x)[i];
    ushort4 u;
    u.x = f2b(v.x); u.y = f2b(v.y); u.z = f2b(v.z); u.w = f2b(v.w);
    ((ushort4*)xb)[i] = u;
  } else {
    int i = (blockIdx.x - 1536) * 256 + threadIdx.x;  // B*128 threads, 4 elems
    int b = i >> 7;
    int e = (i & 127) << 2;
    float4 v = *(const float4*)(cls + e);
    long off = (long)b * (25 * 512) + e;
    ushort4 u;
    u.x = f2b(v.x); u.y = f2b(v.y); u.z = f2b(v.z); u.w = f2b(v.w);
    *(ushort4*)(hb + off) = u;
  }
}

// ---- shared transpose+convert helper: dst[n][k] (bf16) = src[k][n] (f32) ----
__device__ __forceinline__ void conv_tile(const float* __restrict__ src,
                                          u16* __restrict__ dst,
                                          int K, int N, int k0, int n0,
                                          void* smem) {
  float (*t)[65] = (float(*)[65])smem;
  for (int i = threadIdx.x; i < 4096; i += 256) {
    int r = i >> 6, c = i & 63;
    t[r][c] = src[(long)(k0 + r) * N + n0 + c];
  }
  __syncthreads();
  for (int i = threadIdx.x; i < 4096; i += 256) {
    int r = i >> 6, c = i & 63;  // r = n-local, c = k-local
    dst[(long)(n0 + r) * K + k0 + c] = f2b(t[c][r]);
  }
}

// standalone transpose+convert (We)
__global__ __launch_bounds__(256) void convT_kernel(const float* __restrict__ src,
                                                    u16* __restrict__ dst,
                                                    int K, int N,
                                                    long src_gstride, long dst_gstride) {
  __shared__ float t[64][65];
  conv_tile(src + (long)blockIdx.z * src_gstride, dst + (long)blockIdx.z * dst_gstride,
            K, N, blockIdx.x * 64, blockIdx.y * 64, t);
}

// fused per-layer weight convert: Wq(25 groups) + Wk + Wv + Wo, 512x512
__global__ __launch_bounds__(256) void convT4_kernel(
    const float* __restrict__ wq, const float* __restrict__ wk,
    const float* __restrict__ wv, const float* __restrict__ wo,
    u16* __restrict__ dq, u16* __restrict__ dk,
    u16* __restrict__ dv, u16* __restrict__ dwo) {
  __shared__ float t[64][65];
  const int z = blockIdx.z;
  const float* src;
  u16* dst;
  if (z < 25)      { src = wq + (long)z * 262144; dst = dq + (long)z * 262144; }
  else if (z == 25){ src = wk; dst = dk; }
  else if (z == 26){ src = wv; dst = dv; }
  else             { src = wo; dst = dwo; }
  conv_tile(src, dst, 512, 512, blockIdx.x * 64, blockIdx.y * 64, t);
}

// ---------------- GEMM core (128x128, 4 waves): embed + layer-5 o-proj ------
__device__ __forceinline__ void gemm_core(u16* lds,
    const u16* Ag, long a_stride, const u16* Wg, const float* biasg,
    u16* Cg, long c_stride, int K, int m0, int n0) {
  u16* As = lds;            // [128][64] u16, XOR-swizzled
  u16* Bs = lds + 8192;

  const int tid = threadIdx.x;
  const int lane = tid & 63;
  const int wave = tid >> 6;
  const int wr = wave >> 1, wc = wave & 1;

  const int schunk = lane & 7;
  const u16* ga[4];
  const u16* gb[4];
  int lo[4];
#pragma unroll
  for (int i = 0; i < 4; ++i) {
    const int r = wave * 32 + i * 8 + (lane >> 3);
    const int csw = (schunk ^ (r & 7)) << 3;
    ga[i] = Ag + (long)(m0 + r) * a_stride + csw;
    gb[i] = Wg + (long)(n0 + r) * K + csw;
    lo[i] = (wave * 32 + i * 8) * 64;
  }

  f32x4 acc[4][4];
#pragma unroll
  for (int m = 0; m < 4; ++m)
#pragma unroll
    for (int n = 0; n < 4; ++n) {
      acc[m][n][0] = 0.f; acc[m][n][1] = 0.f;
      acc[m][n][2] = 0.f; acc[m][n][3] = 0.f;
    }

  const int nt = K >> 6;
  for (int t = 0; t < nt; ++t) {
    const int k0 = t << 6;
#pragma unroll
    for (int i = 0; i < 4; ++i) {
      gload16(ga[i] + k0, As + lo[i]);
      gload16(gb[i] + k0, Bs + lo[i]);
    }
    __syncthreads();

#pragma unroll
    for (int kk = 0; kk < 64; kk += 32) {
      const int kb = kk + ((lane >> 4) << 3);
      bf16x8 af[4], bfr[4];
#pragma unroll
      for (int m = 0; m < 4; ++m) {
        const int R = (wr << 6) + (m << 4) + (lane & 15);
        af[m] = *(const bf16x8*)&As[((R << 6) + kb) ^ ((R & 7) << 3)];
      }
#pragma unroll
      for (int n = 0; n < 4; ++n) {
        const int Cc = (wc << 6) + (n << 4) + (lane & 15);
        bfr[n] = *(const bf16x8*)&Bs[((Cc << 6) + kb) ^ ((Cc & 7) << 3)];
      }
#pragma unroll
      for (int m = 0; m < 4; ++m)
#pragma unroll
        for (int n = 0; n < 4; ++n)
          acc[m][n] = __builtin_amdgcn_mfma_f32_16x16x32_bf16(af[m], bfr[n],
                                                              acc[m][n], 0, 0, 0);
    }
    if (t + 1 < nt) __syncthreads();
  }

  const int lcol = lane & 15;
  const int lrow = (lane >> 4) << 2;
#pragma unroll
  for (int n = 0; n < 4; ++n) {
    const int col = n0 + (wc << 6) + (n << 4) + lcol;
    const float bv = biasg[col];
#pragma unroll
    for (int m = 0; m < 4; ++m) {
      const int row = m0 + (wr << 6) + (m << 4) + lrow;
#pragma unroll
      for (int j = 0; j < 4; ++j) {
        const float val = acc[m][n][j] + bv;
        Cg[(long)(row + j) * c_stride + col] = f2b(val);
      }
    }
  }
}

// plain grouped wrapper: grid (mtiles, ntiles, groups), XCD-swizzled
__global__ __launch_bounds__(256) void gemm_plain(
    const u16* __restrict__ Abase, long a_stride, long a_goff,
    const u16* __restrict__ Wbase, long w_gstride,
    const float* __restrict__ biasbase, long bias_gstride,
    u16* __restrict__ Cb, long c_stride, long c_goff, int K) {
  __shared__ u16 lds[16384];
  const int gx = gridDim.x, gy = gridDim.y;
  int lin = blockIdx.x + gx * (blockIdx.y + gy * blockIdx.z);
  const int total = gx * gy * gridDim.z;
  const int chunk = total >> 3;
  lin = (lin & 7) * chunk + (lin >> 3);
  const int g = lin / (gx * gy);
  const int rem = lin % (gx * gy);
  const int mt = rem % gx;
  const int nt = rem / gx;
  gemm_core(lds,
            Abase + (long)g * a_goff, a_stride,
            Wbase + (long)g * w_gstride,
            biasbase + (long)g * bias_gstride,
            Cb + (long)g * c_goff, c_stride, K,
            mt * 128, nt * 128);
}

// ---------------- QKV GEMM, 256x256 tile, 8-wave, 8-phase schedule ----------
// BM=BN=256, BK=64, K=512 (8 K-tiles). 8 waves as 2M x 4N; per-wave output
// 128x64 (acc[8][4]). LDS 128KB: 2 K-tile buffers x {A(2 halves),B(2 halves)},
// half = 128 rows x 64 k (16KB), chunk-XOR swizzle via pre-swizzled source.
// Schedule per K-tile t (buf d=t&1): boundary s_barrier (prev ktile's readers
// done -> buf d^1 overwritable), then 4 phases: {stage half-tile ph of ktile
// t+1 into buf d^1 (2 gloads); ph==0: counted s_waitcnt vmcnt(2) (kt t's 8
// loads landed, the 2 just-issued stay in flight); s_barrier+sched_barrier;
// ds_read one quadrant (4 A-frags + 4 B-frags); setprio(1); 16 MFMA;
// setprio(0)}. vmcnt never drains to 0 until the last K-tile.
// Accumulation order (kt asc, kk asc) identical to gemm_core -> same numerics.
__global__ __launch_bounds__(512) void gemm_qkv8(
    const u16* __restrict__ hb,
    const u16* __restrict__ wqT, const u16* __restrict__ wkT, const u16* __restrict__ wvT,
    const float* __restrict__ bq, const float* __restrict__ bk, const float* __restrict__ bv,
    u16* __restrict__ qb, u16* __restrict__ kb, u16* __restrict__ vb) {
  __shared__ u16 lds[65536];          // 128 KB
  const int tid = threadIdx.x;
  const int lane = tid & 63;
  const int wave = tid >> 6;          // 0..7
  const int wr = wave >> 2;           // 0..1  (M half)
  const int wc = wave & 3;            // 0..3  (N quarter)

  // decode: 600 blocks = 8*75, XCD-swizzled. 0..199 Q(g=bid>>3), 200..399 K,
  // 400..599 V. Each matrix: m-tiles x n-tiles; Q per group: 4x2; K/V: 100x2.
  const int bid = (blockIdx.x & 7) * 75 + (blockIdx.x >> 3);
  const u16* Ab; long a_str; const u16* Wt; const float* bias; u16* Cg; long c_str;
  int m0, n0;
  if (bid < 200) {
    const int g = bid >> 3, rem = bid & 7;
    m0 = (rem >> 1) * 256; n0 = (rem & 1) * 256;
    Ab = hb + (long)g * 512; a_str = 12800;
    Wt = wqT + (long)g * 262144; bias = bq + (long)g * 512;
    Cg = qb + (long)g * 512; c_str = 12800;
  } else if (bid < 400) {
    const int rem = bid - 200;
    m0 = (rem >> 1) * 256; n0 = (rem & 1) * 256;
    Ab = hb; a_str = 512; Wt = wkT; bias = bk; Cg = kb; c_str = 512;
  } else {
    const int rem = bid - 400;
    m0 = (rem >> 1) * 256; n0 = (rem & 1) * 256;
    Ab = hb; a_str = 512; Wt = wvT; bias = bv; Cg = vb; c_str = 512;
  }

  // staging precompute: slot j: 0,1 = A halves; 2,3 = B halves. instr i: 2 per
  // half-tile (each covers 64 rows: wave*8 + i*64 .. +7 per lane-group).
  const u16* src[4][2];
  int lo[2];
#pragma unroll
  for (int i = 0; i < 2; ++i) {
    const int r = i * 64 + wave * 8 + (lane >> 3);     // 0..127 within half
    const int csw = (((lane & 7) ^ (r & 7)) << 3);
    lo[i] = (i * 64 + wave * 8) * 64;
#pragma unroll
    for (int j = 0; j < 2; ++j)
      src[j][i] = Ab + (long)(m0 + j * 128 + r) * a_str + csw;
#pragma unroll
    for (int j = 0; j < 2; ++j)
      src[2 + j][i] = Wt + (long)(n0 + j * 128 + r) * 512 + csw;
  }

  f32x4 acc[8][4];
#pragma unroll
  for (int m = 0; m < 8; ++m)
#pragma unroll
    for (int n = 0; n < 4; ++n) {
      acc[m][n][0] = 0.f; acc[m][n][1] = 0.f;
      acc[m][n][2] = 0.f; acc[m][n][3] = 0.f;
    }

  auto STAGE = [&](int kt, int j) {
    const int k0 = kt << 6;
    u16* base = lds + ((j >> 1) << 15) + ((kt & 1) << 14) + ((j & 1) << 13);
#pragma unroll
    for (int i = 0; i < 2; ++i)
      gload16(src[j][i] + k0, base + lo[i]);
  };

  // prologue: stage K-tile 0 (all 4 half-tiles, 8 loads)
#pragma unroll
  for (int j = 0; j < 4; ++j) STAGE(0, j);

  const int lq = lane & 15;
  const int kb0 = (lane >> 4) << 3;
  const int Rb = (wc & 1) << 6;       // B row base within its half

  for (int t = 0; t < 8; ++t) {
    const int d = t & 1;
    const u16* Al = lds + (d << 14) + (wr << 13);
    const u16* Bl = lds + 32768 + (d << 14) + ((wc >> 1) << 13);

    __builtin_amdgcn_s_barrier();       // boundary: prev ktile's reads done
    __builtin_amdgcn_sched_barrier(0);

#pragma unroll
    for (int ph = 0; ph < 4; ++ph) {
      if (t < 7) STAGE(t + 1, ph);      // 2 loads into buf d^1, stay in flight
      if (ph == 0) {
        if (t < 7) asm volatile("s_waitcnt vmcnt(2)" ::: "memory");
        else       asm volatile("s_waitcnt vmcnt(0)" ::: "memory");
      }
      __builtin_amdgcn_s_barrier();     // publish (ph0) / phase-lock (ph1-3)
      __builtin_amdgcn_sched_barrier(0);

      const int mfb = (ph & 1) << 2;          // quadrant rows: 0-3 or 4-7
      const int kb = ((ph >> 1) << 5) + kb0;  // kk = 0 or 32
      bf16x8 af[4], bfr[4];
#pragma unroll
      for (int q = 0; q < 4; ++q) {
        const int R = ((mfb + q) << 4) + lq;
        af[q] = *(const bf16x8*)&Al[((R << 6) + kb) ^ ((R & 7) << 3)];
      }
#pragma unroll
      for (int nf = 0; nf < 4; ++nf) {
        const int R = Rb + (nf << 4) + lq;
        bfr[nf] = *(const bf16x8*)&Bl[((R << 6) + kb) ^ ((R & 7) << 3)];
      }
      __builtin_amdgcn_s_setprio(1);
#pragma unroll
      for (int q = 0; q < 4; ++q)
#pragma unroll
        for (int nf = 0; nf < 4; ++nf)
          acc[mfb + q][nf] = __builtin_amdgcn_mfma_f32_16x16x32_bf16(
              af[q], bfr[nf], acc[mfb + q][nf], 0, 0, 0);
      __builtin_amdgcn_s_setprio(0);
    }
  }

  // epilogue: C/D layout col=lane&15, row=(lane>>4)*4+e (HW-verified)
  const int lrow = (lane >> 4) << 2;
#pragma unroll
  for (int nf = 0; nf < 4; ++nf) {
    const int col = n0 + (wc << 6) + (nf << 4) + lq;
    const float bv = bias[col];
#pragma unroll
    for (int mf = 0; mf < 8; ++mf) {
      const int row = m0 + (wr << 7) + (mf << 4) + lrow;
#pragma unroll
      for (int e = 0; e < 4; ++e)
        Cg[(long)(row + e) * c_str + col] = f2b(acc[mf][nf][e] + bv);
    }
  }
}

// ---------------- attention: wave per (batch, head), fp32-staged K/V --------
__global__ __launch_bounds__(256) void attn_kernel(const u16* __restrict__ q,
                                                   u16* __restrict__ kio,
                                                   const u16* __restrict__ v) {
  __shared__ float ks_[25 * 256];
  __shared__ float vs_[25 * 256];
  const int tid = threadIdx.x;
  const int b = blockIdx.x >> 1;
  const int h0 = blockIdx.x & 1;      // head-group (4 heads)
  const long base = (long)b * 25 * 512;

  for (int i = tid; i < 800; i += 256) {
    const int j = i >> 5, c = i & 31;
    const long goff = base + (long)j * 512 + h0 * 256 + c * 8;
    uint4 kt = *(const uint4*)(kio + goff);
    uint4 vt = *(const uint4*)(v + goff);
    const u32 ka[4] = {kt.x, kt.y, kt.z, kt.w};
    const u32 va[4] = {vt.x, vt.y, vt.z, vt.w};
    float4 k0f = {b2f((u16)ka[0]), b2f((u16)(ka[0] >> 16)),
                  b2f((u16)ka[1]), b2f((u16)(ka[1] >> 16))};
    float4 k1f = {b2f((u16)ka[2]), b2f((u16)(ka[2] >> 16)),
                  b2f((u16)ka[3]), b2f((u16)(ka[3] >> 16))};
    float4 v0f = {b2f((u16)va[0]), b2f((u16)(va[0] >> 16)),
                  b2f((u16)va[1]), b2f((u16)(va[1] >> 16))};
    float4 v1f = {b2f((u16)va[2]), b2f((u16)(va[2] >> 16)),
                  b2f((u16)va[3]), b2f((u16)(va[3] >> 16))};
    const int off = j * 256 + c * 8;
    *(float4*)&ks_[off]     = k0f;
    *(float4*)&ks_[off + 4] = k1f;
    *(float4*)&vs_[off]     = v0f;
    *(float4*)&vs_[off + 4] = v1f;
  }
  __syncthreads();

  const int w = tid >> 6;
  const int lane = tid & 63;
  const int qi = lane >> 1;
  const int half = lane & 1;
  if (qi < 25) {
    const int h = h0 * 4 + w;
    const int dslice = w * 64 + half * 32;

    const u16* qrow = q + base + (long)qi * 512 + h * 64 + half * 32;
    float buf[32];
#pragma unroll
    for (int c = 0; c < 4; ++c) {
      uint4 t = *(const uint4*)(qrow + c * 8);
      const u32 tt[4] = {t.x, t.y, t.z, t.w};
#pragma unroll
      for (int e = 0; e < 4; ++e) {
        buf[c * 8 + 2 * e]     = b2f((u16)tt[e]);
        buf[c * 8 + 2 * e + 1] = b2f((u16)(tt[e] >> 16));
      }
    }

    float sc[25];
    float mx = -1e30f;
#pragma unroll
    for (int j = 0; j < 25; ++j) {
      const float4* kr = (const float4*)&ks_[j * 256 + dslice];
      float s0 = 0.f, s1 = 0.f;
#pragma unroll
      for (int c4 = 0; c4 < 8; ++c4) {
        float4 kv = kr[c4];
        s0 += buf[4 * c4 + 0] * kv.x + buf[4 * c4 + 1] * kv.y;
        s1 += buf[4 * c4 + 2] * kv.z + buf[4 * c4 + 3] * kv.w;
      }
      float s = s0 + s1;
      s += __shfl_xor(s, 1);
      s *= 0.125f;
      sc[j] = s;
      mx = fmaxf(mx, s);
    }
    float sum = 0.f;
#pragma unroll
    for (int j = 0; j < 25; ++j) {
      sc[j] = __expf(sc[j] - mx);
      sum += sc[j];
    }
    const float inv = 1.f / sum;

#pragma unroll
    for (int d = 0; d < 32; ++d) buf[d] = 0.f;
#pragma unroll
    for (int j = 0; j < 25; ++j) {
      const float wj = sc[j];
      const float4* vr = (const float4*)&vs_[j * 256 + dslice];
#pragma unroll
      for (int c4 = 0; c4 < 8; ++c4) {
        float4 vv = vr[c4];
        buf[4 * c4 + 0] += wj * vv.x;
        buf[4 * c4 + 1] += wj * vv.y;
        buf[4 * c4 + 2] += wj * vv.z;
        buf[4 * c4 + 3] += wj * vv.w;
      }
    }

    u16* orow = kio + base + (long)qi * 512 + h * 64 + half * 32;
#pragma unroll
    for (int c = 0; c < 4; ++c) {
      uint4 t;
      u32 tt[4];
#pragma unroll
      for (int e = 0; e < 4; ++e)
        tt[e] = (u32)f2b(buf[c * 8 + 2 * e] * inv) |
                ((u32)f2b(buf[c * 8 + 2 * e + 1] * inv) << 16);
      t.x = tt[0]; t.y = tt[1]; t.z = tt[2]; t.w = tt[3];
      *(uint4*)(orow + c * 8) = t;
    }
  }
}

// ---------------- O-proj + residual + LayerNorm fused (layers 0-4) ----------
// NEVER writes d_out (would race with woT scratch readers — round-9 NaN).
__global__ __launch_bounds__(512) void gemm_oln(
    const u16* __restrict__ ao,       // attn out (kb) [25600][512] bf16
    const u16* __restrict__ woT,      // [512][512] bf16 (N-major)
    const float* __restrict__ bo,
    u16* __restrict__ hb,             // residual in/out (bf16)
    const float* __restrict__ gam, const float* __restrict__ bet) {
  __shared__ u16 As[4096];            // 64x64 bf16 (8KB)
  __shared__ u16 Bs[32768];           // 512x64 bf16 (64KB); reused as C[64][512]
  const int tid = threadIdx.x;
  const int lane = tid & 63;
  const int wave = tid >> 6;          // 0..7 = output col-block
  const int mb = (int)(blockIdx.x & 7) * 50 + (int)(blockIdx.x >> 3);  // 400=8*50
  const int m0 = mb * 64;

  const int sr = tid >> 3;                       // 0..63
  const int schunk = ((tid & 7) ^ (sr & 7)) << 3;
  const int aoff = (m0 + sr) * 512 + schunk;
  int boff[8];
#pragma unroll
  for (int i = 0; i < 8; ++i) boff[i] = (i * 64 + sr) * 512 + schunk;
  const int lA = (wave << 3) << 6;
  int lB[8];
#pragma unroll
  for (int i = 0; i < 8; ++i) lB[i] = ((i * 64 + (wave << 3))) << 6;

  f32x4 acc[4][4];
#pragma unroll
  for (int m = 0; m < 4; ++m)
#pragma unroll
    for (int n = 0; n < 4; ++n) {
      acc[m][n][0] = 0.f; acc[m][n][1] = 0.f;
      acc[m][n][2] = 0.f; acc[m][n][3] = 0.f;
    }

  for (int t = 0; t < 8; ++t) {
    const int k0 = t << 6;
    gload16(ao + aoff + k0, As + lA);
#pragma unroll
    for (int i = 0; i < 8; ++i) gload16(woT + boff[i] + k0, Bs + lB[i]);
    __syncthreads();

#pragma unroll
    for (int kk = 0; kk < 64; kk += 32) {
      const int kb = kk + ((lane >> 4) << 3);
      bf16x8 af[4], bfr[4];
#pragma unroll
      for (int m = 0; m < 4; ++m) {
        const int R = (m << 4) + (lane & 15);          // rows 0..63
        af[m] = *(const bf16x8*)&As[((R << 6) + kb) ^ ((R & 7) << 3)];
      }
#pragma unroll
      for (int n = 0; n < 4; ++n) {
        const int Cc = (wave << 6) + (n << 4) + (lane & 15);  // 0..511
        bfr[n] = *(const bf16x8*)&Bs[((Cc << 6) + kb) ^ ((Cc & 7) << 3)];
      }
#pragma unroll
      for (int m = 0; m < 4; ++m)
#pragma unroll
        for (int n = 0; n < 4; ++n)
          acc[m][n] = __builtin_amdgcn_mfma_f32_16x16x32_bf16(af[m], bfr[n],
                                                              acc[m][n], 0, 0, 0);
    }
    __syncthreads();   // WAR for next stage; after t==7: fences the C overwrite
  }

  // epilogue 1: C = acc + bias -> Bs as bf16 [64][512], chunk-XOR swizzle
  u16* C = Bs;
  {
    const int lcol = lane & 15;
    const int lrow = (lane >> 4) << 2;
#pragma unroll
    for (int n = 0; n < 4; ++n) {
      const int col = (wave << 6) + (n << 4) + lcol;
      const float bv = bo[col];
#pragma unroll
      for (int m = 0; m < 4; ++m) {
#pragma unroll
        for (int j = 0; j < 4; ++j) {
          const int row = (m << 4) + lrow + j;
          C[((row << 9) + col) ^ ((row & 7) << 3)] = f2b(acc[m][n][j] + bv);
        }
      }
    }
  }
  __syncthreads();

  // epilogue 2: residual + LN, wave-per-row (8 rows per wave)
  const int ebase = lane << 3;
#pragma unroll
  for (int rr = 0; rr < 8; ++rr) {
    const int row = (rr << 3) + wave;
    uint4 cv = *(const uint4*)&C[((row << 9) + ebase) ^ ((row & 7) << 3)];
    const long grow = (long)(m0 + row) * 512;
    uint4 hv4 = *(const uint4*)(hb + grow + ebase);
    const u32 ha[4] = {hv4.x, hv4.y, hv4.z, hv4.w};
    const u32 oa[4] = {cv.x, cv.y, cv.z, cv.w};
    float y[8];
#pragma unroll
    for (int e = 0; e < 4; ++e) {
      y[2 * e]     = b2f((u16)ha[e])         + b2f((u16)oa[e]);
      y[2 * e + 1] = b2f((u16)(ha[e] >> 16)) + b2f((u16)(oa[e] >> 16));
    }
    float s = 0.f, ss = 0.f;
#pragma unroll
    for (int i = 0; i < 8; ++i) { s += y[i]; ss += y[i] * y[i]; }
#pragma unroll
    for (int off = 32; off > 0; off >>= 1) {
      s += __shfl_down(s, off);
      ss += __shfl_down(ss, off);
    }
    s = __shfl(s, 0);
    ss = __shfl(ss, 0);
    const float mean = s * (1.f / 512.f);
    const float var = ss * (1.f / 512.f) - mean * mean;
    const float rinv = rsqrtf(var + 1e-5f);
    float4 g0 = *(const float4*)(gam + ebase);
    float4 g1 = *(const float4*)(gam + ebase + 4);
    float4 b0 = *(const float4*)(bet + ebase);
    float4 b1 = *(const float4*)(bet + ebase + 4);
    float r[8];
    r[0] = (y[0] - mean) * rinv * g0.x + b0.x;
    r[1] = (y[1] - mean) * rinv * g0.y + b0.y;
    r[2] = (y[2] - mean) * rinv * g0.z + b0.z;
    r[3] = (y[3] - mean) * rinv * g0.w + b0.w;
    r[4] = (y[4] - mean) * rinv * g1.x + b1.x;
    r[5] = (y[5] - mean) * rinv * g1.y + b1.y;
    r[6] = (y[6] - mean) * rinv * g1.z + b1.z;
    r[7] = (y[7] - mean) * rinv * g1.w + b1.w;
    uint4 hv;
    hv.x = (u32)f2b(r[0]) | ((u32)f2b(r[1]) << 16);
    hv.y = (u32)f2b(r[2]) | ((u32)f2b(r[3]) << 16);
    hv.z = (u32)f2b(r[4]) | ((u32)f2b(r[5]) << 16);
    hv.w = (u32)f2b(r[6]) | ((u32)f2b(r[7]) << 16);
    *(uint4*)(hb + grow + ebase) = hv;
  }
}

// ---------------- residual + LayerNorm standalone (layer 5) -----------------
__global__ __launch_bounds__(256) void ln_kernel(u16* hb,
                                                 const u16* __restrict__ o,
                                                 const float* __restrict__ g,
                                                 const float* __restrict__ bta,
                                                 float* fout) {
  const int lane = threadIdx.x & 63;
  const int wave = threadIdx.x >> 6;
  const long row = (long)blockIdx.x * 4 + wave;
  u16* hr = hb + row * 512;
  const u16* orow = o + row * 512;
  const int base = lane << 3;
  uint4 hv4 = *(const uint4*)(hr + base);
  uint4 ov = *(const uint4*)(orow + base);
  const u32 ha[4] = {hv4.x, hv4.y, hv4.z, hv4.w};
  const u32 oa[4] = {ov.x, ov.y, ov.z, ov.w};
  float y[8];
#pragma unroll
  for (int e = 0; e < 4; ++e) {
    y[2 * e]     = b2f((u16)ha[e])         + b2f((u16)oa[e]);
    y[2 * e + 1] = b2f((u16)(ha[e] >> 16)) + b2f((u16)(oa[e] >> 16));
  }
  float s = 0.f, ss = 0.f;
#pragma unroll
  for (int i = 0; i < 8; ++i) { s += y[i]; ss += y[i] * y[i]; }
#pragma unroll
  for (int off = 32; off > 0; off >>= 1) {
    s += __shfl_down(s, off);
    ss += __shfl_down(ss, off);
  }
  s = __shfl(s, 0);
  ss = __shfl(ss, 0);
  const float mean = s * (1.f / 512.f);
  const float var = ss * (1.f / 512.f) - mean * mean;
  const float rinv = rsqrtf(var + 1e-5f);
  float4 g0 = *(const float4*)(g + base);
  float4 g1 = *(const float4*)(g + base + 4);
  float4 b0 = *(const float4*)(bta + base);
  float4 b1 = *(const float4*)(bta + base + 4);
  float r[8];
  r[0] = (y[0] - mean) * rinv * g0.x + b0.x;
  r[1] = (y[1] - mean) * rinv * g0.y + b0.y;
  r[2] = (y[2] - mean) * rinv * g0.z + b0.z;
  r[3] = (y[3] - mean) * rinv * g0.w + b0.w;
  r[4] = (y[4] - mean) * rinv * g1.x + b1.x;
  r[5] = (y[5] - mean) * rinv * g1.y + b1.y;
  r[6] = (y[6] - mean) * rinv * g1.z + b1.z;
  r[7] = (y[7] - mean) * rinv * g1.w + b1.w;
  uint4 hv;
  hv.x = (u32)f2b(r[0]) | ((u32)f2b(r[1]) << 16);
  hv.y = (u32)f2b(r[2]) | ((u32)f2b(r[3]) << 16);
  hv.z = (u32)f2b(r[4]) | ((u32)f2b(r[5]) << 16);
  hv.w = (u32)f2b(r[6]) | ((u32)f2b(r[7]) << 16);
  *(uint4*)(hr + base) = hv;
  if (fout) {
    float* fr = fout + row * 512 + base;
    float4 w0 = {r[0], r[1], r[2], r[3]};
    float4 w1 = {r[4], r[5], r[6], r[7]};
    *(float4*)(fr) = w0;
    *(float4*)(fr + 4) = w1;
  }
}

// ---------------- host launcher ----------------
// d_in: x, We, be, cls, Wk, bk, Wv, bv, Wq, bq, Wo, bo, ln_g, ln_b
// ws (100 MiB): hb@0, kb@25M(=xb alias), vb@50M, qb@75M
// d_out doubles as bf16 weight scratch; layer 5 runs the UNFUSED o-proj+ln
// path so no kernel both reads scratch and writes d_out.
extern "C" void kernel_launch(void* const* d_in, const int* in_sizes, int n_in,
                              void* d_out, int out_size, void* d_ws, size_t ws_size,
                              hipStream_t stream) {
  const float* x   = (const float*)d_in[0];
  const float* We  = (const float*)d_in[1];
  const float* be  = (const float*)d_in[2];
  const float* cls = (const float*)d_in[3];
  const float* Wk  = (const float*)d_in[4];
  const float* bk  = (const float*)d_in[5];
  const float* Wv  = (const float*)d_in[6];
  const float* bv  = (const float*)d_in[7];
  const float* Wq  = (const float*)d_in[8];
  const float* bq  = (const float*)d_in[9];
  const float* Wo  = (const float*)d_in[10];
  const float* bo  = (const float*)d_in[11];
  const float* lng = (const float*)d_in[12];
  const float* lnb = (const float*)d_in[13];
  float* out = (float*)d_out;

  char* ws = (char*)d_ws;
  u16* hb = (u16*)ws;
  u16* kb = (u16*)(ws + 26214400);
  u16* vb = (u16*)(ws + 52428800);
  u16* qb = (u16*)(ws + 78643200);
  u16* xb = kb;  // alias: consumed by embed GEMM before K written

  // weight scratch in d_out (bf16 view)
  u16* scr = (u16*)d_out;
  u16* weT = scr + 7340032;
  u16* wqT = scr;                    // 6,553,600
  u16* wkT = scr + 6553600;          // 262,144
  u16* wvT = scr + 6815744;          // 262,144
  u16* woT = scr + 7077888;          // 262,144

  // prologue: cast+cls; convert We^T; embed GEMM -> hb
  prep_kernel<<<2048, 256, 0, stream>>>(x, cls, xb, hb);
  convT_kernel<<<dim3(1, 8, 24), 256, 0, stream>>>(We, weT, 64, 512, 32768, 32768);
  gemm_plain<<<dim3(8, 4, 24), 256, 0, stream>>>(
      xb, 1536, 64, weT, 32768, be, 512, hb + 512, 12800, 512, 64);

  for (int l = 0; l < 6; ++l) {
    convT4_kernel<<<dim3(8, 8, 28), 256, 0, stream>>>(
        Wq + (long)l * 6553600, Wk + (long)l * 262144,
        Wv + (long)l * 262144, Wo + (long)l * 262144,
        wqT, wkT, wvT, woT);
    gemm_qkv8<<<600, 512, 0, stream>>>(
        hb, wqT, wkT, wvT,
        bq + (long)l * 12800, bk + (long)l * 512, bv + (long)l * 512,
        qb, kb, vb);
    attn_kernel<<<2048, 256, 0, stream>>>(qb, kb, vb);
    if (l < 5) {
      gemm_oln<<<400, 512, 0, stream>>>(
          kb, woT, bo + (long)l * 512, hb,
          lng + (long)l * 512, lnb + (long)l * 512);
    } else {
      // layer 5: unfused (gemm_oln would read woT scratch in d_out while
      // writing d_out -> cross-block race, round-9 NaN)
      gemm_plain<<<dim3(200, 4, 1), 256, 0, stream>>>(
          kb, 512, 0, woT, 0, bo + (long)l * 512, 0, qb, 512, 0, 512);
      ln_kernel<<<6400, 256, 0, stream>>>(hb, qb, lng + l * 512, lnb + l * 512, out);
    }
  }
}

// Round 13
// 1009.947 us; speedup vs baseline: 1.1146x; 1.1146x over previous
//
#include <hip/hip_runtime.h>

typedef unsigned short u16;
typedef unsigned int u32;
typedef short bf16x8 __attribute__((ext_vector_type(8)));
typedef float f32x4 __attribute__((ext_vector_type(4)));

#define AS1 __attribute__((address_space(1)))
#define AS3 __attribute__((address_space(3)))

__device__ __forceinline__ u16 f2b(float f) {
  u32 u = __float_as_uint(f);
  u += 0x7fffu + ((u >> 16) & 1u);   // round-to-nearest-even
  return (u16)(u >> 16);
}
__device__ __forceinline__ float b2f(u16 s) {
  return __uint_as_float(((u32)s) << 16);
}

__device__ __forceinline__ void gload16(const u16* g, u16* l) {
  __builtin_amdgcn_global_load_lds((const AS1 void*)g, (AS3 void*)l, 16, 0, 0);
}

// ---------------- cast x (f32) -> bf16 ----------------
__global__ __launch_bounds__(256) void cast_kernel(const float* __restrict__ x,
                                                   u16* __restrict__ xb, int n4) {
  int i = blockIdx.x * 256 + threadIdx.x;
  if (i >= n4) return;
  float4 v = ((const float4*)x)[i];
  ushort4 u;
  u.x = f2b(v.x); u.y = f2b(v.y); u.z = f2b(v.z); u.w = f2b(v.w);
  ((ushort4*)xb)[i] = u;
}

// ---------------- fill cls rows (token 0, bf16 residual) ----------------
__global__ __launch_bounds__(256) void cls_kernel(const float* __restrict__ cls,
                                                  u16* __restrict__ hb) {
  int i = blockIdx.x * 256 + threadIdx.x;  // B*128 threads, 4 elems each
  int b = i >> 7;
  int e = (i & 127) << 2;
  float4 v = *(const float4*)(cls + e);
  long off = (long)b * (25 * 512) + e;
  ushort4 u;
  u.x = f2b(v.x); u.y = f2b(v.y); u.z = f2b(v.z); u.w = f2b(v.w);
  *(ushort4*)(hb + off) = u;
}

// ---- shared transpose+convert helper: dst[n][k] (bf16) = src[k][n] (f32) ----
__device__ __forceinline__ void conv_tile(const float* __restrict__ src,
                                          u16* __restrict__ dst,
                                          int K, int N, int k0, int n0,
                                          void* smem) {
  float (*t)[65] = (float(*)[65])smem;
  for (int i = threadIdx.x; i < 4096; i += 256) {
    int r = i >> 6, c = i & 63;
    t[r][c] = src[(long)(k0 + r) * N + n0 + c];
  }
  __syncthreads();
  for (int i = threadIdx.x; i < 4096; i += 256) {
    int r = i >> 6, c = i & 63;  // r = n-local, c = k-local
    dst[(long)(n0 + r) * K + k0 + c] = f2b(t[c][r]);
  }
}

// standalone transpose+convert (We)
__global__ __launch_bounds__(256) void convT_kernel(const float* __restrict__ src,
                                                    u16* __restrict__ dst,
                                                    int K, int N,
                                                    long src_gstride, long dst_gstride) {
  __shared__ float t[64][65];
  conv_tile(src + (long)blockIdx.z * src_gstride, dst + (long)blockIdx.z * dst_gstride,
            K, N, blockIdx.x * 64, blockIdx.y * 64, t);
}

// fused per-layer weight convert: Wq(25 groups) + Wk + Wv + Wo, 512x512
__global__ __launch_bounds__(256) void convT4_kernel(
    const float* __restrict__ wq, const float* __restrict__ wk,
    const float* __restrict__ wv, const float* __restrict__ wo,
    u16* __restrict__ dq, u16* __restrict__ dk,
    u16* __restrict__ dv, u16* __restrict__ dwo) {
  __shared__ float t[64][65];
  const int z = blockIdx.z;
  const float* src;
  u16* dst;
  if (z < 25)      { src = wq + (long)z * 262144; dst = dq + (long)z * 262144; }
  else if (z == 25){ src = wk; dst = dk; }
  else if (z == 26){ src = wv; dst = dv; }
  else             { src = wo; dst = dwo; }
  conv_tile(src, dst, 512, 512, blockIdx.x * 64, blockIdx.y * 64, t);
}

// ---------------- GEMM core: C = A @ Wt^T + bias ----------------
// 128x128 tile, 4 waves, BK=64, 2-phase double-buffered (the 999.9us config):
// issue next tile's global_load_lds into buf^1 BEFORE computing buf; one
// __syncthreads() per K-step (its vmcnt(0)+lgkmcnt(0) drain is the wait).
__device__ __forceinline__ void gemm_core(u16* lds,
    const u16* Ag, long a_stride, const u16* Wg, const float* biasg,
    u16* Cg, long c_stride, int K, int m0, int n0) {
  u16* As0 = lds;
  u16* Bs0 = lds + 8192;
  u16* As1 = lds + 16384;
  u16* Bs1 = lds + 24576;

  const int tid = threadIdx.x;
  const int lane = tid & 63;
  const int wave = tid >> 6;
  const int wr = wave >> 1, wc = wave & 1;

  const int schunk = lane & 7;
  const u16* ga[4];
  const u16* gb[4];
  int lo[4];
#pragma unroll
  for (int i = 0; i < 4; ++i) {
    const int r = wave * 32 + i * 8 + (lane >> 3);
    const int csw = (schunk ^ (r & 7)) << 3;
    ga[i] = Ag + (long)(m0 + r) * a_stride + csw;
    gb[i] = Wg + (long)(n0 + r) * K + csw;
    lo[i] = (wave * 32 + i * 8) * 64;
  }

  f32x4 acc[4][4];
#pragma unroll
  for (int m = 0; m < 4; ++m)
#pragma unroll
    for (int n = 0; n < 4; ++n) {
      acc[m][n][0] = 0.f; acc[m][n][1] = 0.f;
      acc[m][n][2] = 0.f; acc[m][n][3] = 0.f;
    }

  auto STAGE = [&](int k0, u16* A, u16* B) {
#pragma unroll
    for (int i = 0; i < 4; ++i) {
      gload16(ga[i] + k0, A + lo[i]);
      gload16(gb[i] + k0, B + lo[i]);
    }
  };
  auto COMPUTE = [&](const u16* A, const u16* B) {
#pragma unroll
    for (int kk = 0; kk < 64; kk += 32) {
      const int kb = kk + ((lane >> 4) << 3);
      bf16x8 af[4], bfr[4];
#pragma unroll
      for (int m = 0; m < 4; ++m) {
        const int R = (wr << 6) + (m << 4) + (lane & 15);
        af[m] = *(const bf16x8*)&A[((R << 6) + kb) ^ ((R & 7) << 3)];
      }
#pragma unroll
      for (int n = 0; n < 4; ++n) {
        const int Cc = (wc << 6) + (n << 4) + (lane & 15);
        bfr[n] = *(const bf16x8*)&B[((Cc << 6) + kb) ^ ((Cc & 7) << 3)];
      }
#pragma unroll
      for (int m = 0; m < 4; ++m)
#pragma unroll
        for (int n = 0; n < 4; ++n)
          acc[m][n] = __builtin_amdgcn_mfma_f32_16x16x32_bf16(af[m], bfr[n],
                                                              acc[m][n], 0, 0, 0);
    }
  };

  const int nt = K >> 6;
  STAGE(0, As0, Bs0);
  __syncthreads();                       // tile 0 resident (vmcnt0 drain)
  for (int t = 0; t < nt; ++t) {
    u16* cA = (t & 1) ? As1 : As0;
    u16* cB = (t & 1) ? Bs1 : Bs0;
    if (t + 1 < nt) {
      u16* nA = (t & 1) ? As0 : As1;
      u16* nB = (t & 1) ? Bs0 : Bs1;
      STAGE((t + 1) << 6, nA, nB);       // in flight during compute
    }
    COMPUTE(cA, cB);
    if (t + 1 < nt) __syncthreads();     // drains next tile's loads + WAR fence
  }

  const int lcol = lane & 15;
  const int lrow = (lane >> 4) << 2;
#pragma unroll
  for (int n = 0; n < 4; ++n) {
    const int col = n0 + (wc << 6) + (n << 4) + lcol;
    const float bv = biasg[col];
#pragma unroll
    for (int m = 0; m < 4; ++m) {
      const int row = m0 + (wr << 6) + (m << 4) + lrow;
#pragma unroll
      for (int j = 0; j < 4; ++j) {
        const float val = acc[m][n][j] + bv;
        Cg[(long)(row + j) * c_stride + col] = f2b(val);
      }
    }
  }
}

// plain grouped wrapper: grid (mtiles, ntiles, groups), XCD-swizzled
__global__ __launch_bounds__(256) void gemm_plain(
    const u16* __restrict__ Abase, long a_stride, long a_goff,
    const u16* __restrict__ Wbase, long w_gstride,
    const float* __restrict__ biasbase, long bias_gstride,
    u16* __restrict__ Cb, long c_stride, long c_goff, int K) {
  __shared__ u16 lds[4 * 8192];
  const int gx = gridDim.x, gy = gridDim.y;
  int lin = blockIdx.x + gx * (blockIdx.y + gy * blockIdx.z);
  const int total = gx * gy * gridDim.z;
  const int chunk = total >> 3;
  lin = (lin & 7) * chunk + (lin >> 3);   // XCD-contiguous work chunks
  const int g = lin / (gx * gy);
  const int rem = lin % (gx * gy);
  const int mt = rem % gx;
  const int nt = rem / gx;
  gemm_core(lds,
            Abase + (long)g * a_goff, a_stride,
            Wbase + (long)g * w_gstride,
            biasbase + (long)g * bias_gstride,
            Cb + (long)g * c_goff, c_stride, K,
            mt * 128, nt * 128);
}

// fused Q(25 groups)+K+V: 1D grid of 2400 blocks, XCD-swizzled (2400 = 8*300)
__global__ __launch_bounds__(256) void gemm_qkv(
    const u16* __restrict__ hb,
    const u16* __restrict__ wqT, const u16* __restrict__ wkT, const u16* __restrict__ wvT,
    const float* __restrict__ bq, const float* __restrict__ bk, const float* __restrict__ bv,
    u16* __restrict__ qb, u16* __restrict__ kb, u16* __restrict__ vb) {
  __shared__ u16 lds[4 * 8192];
  const int bid = (blockIdx.x & 7) * 300 + (blockIdx.x >> 3);
  const u16* Ag; long a_str; const u16* Wg; const float* bg; u16* Cg; long c_str;
  int mt, nt;
  if (bid < 800) {           // Q: per-joint groups
    const int g = bid >> 5, rem = bid & 31;
    mt = rem >> 2; nt = rem & 3;
    Ag = hb + (long)g * 512; a_str = 12800;
    Wg = wqT + (long)g * 262144; bg = bq + (long)g * 512;
    Cg = qb + (long)g * 512; c_str = 12800;
  } else if (bid < 1600) {   // K
    const int rem = bid - 800;
    mt = rem >> 2; nt = rem & 3;
    Ag = hb; a_str = 512; Wg = wkT; bg = bk; Cg = kb; c_str = 512;
  } else {                   // V
    const int rem = bid - 1600;
    mt = rem >> 2; nt = rem & 3;
    Ag = hb; a_str = 512; Wg = wvT; bg = bv; Cg = vb; c_str = 512;
  }
  gemm_core(lds, Ag, a_str, Wg, bg, Cg, c_str, 512, mt * 128, nt * 128);
}

// ---------------- attention: wave per (batch, head), bf16 LDS (999.9 config) -
__global__ __launch_bounds__(256) void attn_kernel(const u16* __restrict__ q,
                                                   u16* __restrict__ kio,
                                                   const u16* __restrict__ v) {
  __shared__ u16 ks_[25 * 256];
  __shared__ u16 vs_[25 * 256];
  const int tid = threadIdx.x;
  const int b = blockIdx.x >> 1;
  const int h0 = blockIdx.x & 1;      // head-group (4 heads)
  const long base = (long)b * 25 * 512;

  for (int i = tid; i < 800; i += 256) {
    const int j = i >> 5, c = i & 31;
    const long goff = base + (long)j * 512 + h0 * 256 + c * 8;
    ((uint4*)ks_)[i] = *(const uint4*)(kio + goff);
    ((uint4*)vs_)[i] = *(const uint4*)(v + goff);
  }
  __syncthreads();

  const int w = tid >> 6;
  const int lane = tid & 63;
  const int qi = lane >> 1;
  const int half = lane & 1;
  if (qi < 25) {
    const int h = h0 * 4 + w;
    const int dslice = w * 64 + half * 32;

    const u16* qrow = q + base + (long)qi * 512 + h * 64 + half * 32;
    float buf[32];
#pragma unroll
    for (int c = 0; c < 4; ++c) {
      uint4 t = *(const uint4*)(qrow + c * 8);
      const u32 tt[4] = {t.x, t.y, t.z, t.w};
#pragma unroll
      for (int e = 0; e < 4; ++e) {
        buf[c * 8 + 2 * e]     = b2f((u16)tt[e]);
        buf[c * 8 + 2 * e + 1] = b2f((u16)(tt[e] >> 16));
      }
    }

    float sc[25];
    float mx = -1e30f;
#pragma unroll
    for (int j = 0; j < 25; ++j) {
      float s = 0.f;
      const u16* kr = &ks_[j * 256 + dslice];
#pragma unroll
      for (int d = 0; d < 32; d += 2) {
        u32 t = *(const u32*)(kr + d);
        s += buf[d] * b2f((u16)t) + buf[d + 1] * b2f((u16)(t >> 16));
      }
      s += __shfl_xor(s, 1);
      s *= 0.125f;
      sc[j] = s;
      mx = fmaxf(mx, s);
    }
    float sum = 0.f;
#pragma unroll
    for (int j = 0; j < 25; ++j) {
      sc[j] = __expf(sc[j] - mx);
      sum += sc[j];
    }
    const float inv = 1.f / sum;

#pragma unroll
    for (int d = 0; d < 32; ++d) buf[d] = 0.f;
#pragma unroll
    for (int j = 0; j < 25; ++j) {
      const float wj = sc[j];
      const u16* vr = &vs_[j * 256 + dslice];
#pragma unroll
      for (int d = 0; d < 32; d += 2) {
        u32 t = *(const u32*)(vr + d);
        buf[d]     += wj * b2f((u16)t);
        buf[d + 1] += wj * b2f((u16)(t >> 16));
      }
    }

    u16* orow = kio + base + (long)qi * 512 + h * 64 + half * 32;
#pragma unroll
    for (int c = 0; c < 4; ++c) {
      uint4 t;
      u32 tt[4];
#pragma unroll
      for (int e = 0; e < 4; ++e)
        tt[e] = (u32)f2b(buf[c * 8 + 2 * e] * inv) |
                ((u32)f2b(buf[c * 8 + 2 * e + 1] * inv) << 16);
      t.x = tt[0]; t.y = tt[1]; t.z = tt[2]; t.w = tt[3];
      *(uint4*)(orow + c * 8) = t;
    }
  }
}

// ---------------- O-proj + residual + LayerNorm fused (layers 0-4) ----------
// NEVER writes d_out (would race with woT scratch readers — round-9 NaN).
__global__ __launch_bounds__(512) void gemm_oln(
    const u16* __restrict__ ao,       // attn out (kb) [25600][512] bf16
    const u16* __restrict__ woT,      // [512][512] bf16 (N-major)
    const float* __restrict__ bo,
    u16* __restrict__ hb,             // residual in/out (bf16)
    const float* __restrict__ gam, const float* __restrict__ bet) {
  __shared__ u16 As[4096];            // 64x64 bf16 (8KB)
  __shared__ u16 Bs[32768];           // 512x64 bf16 (64KB); reused as C[64][512]
  const int tid = threadIdx.x;
  const int lane = tid & 63;
  const int wave = tid >> 6;          // 0..7 = output col-block
  const int mb = (int)(blockIdx.x & 7) * 50 + (int)(blockIdx.x >> 3);  // 400=8*50
  const int m0 = mb * 64;

  const int sr = tid >> 3;                       // 0..63
  const int schunk = ((tid & 7) ^ (sr & 7)) << 3;
  const int aoff = (m0 + sr) * 512 + schunk;
  int boff[8];
#pragma unroll
  for (int i = 0; i < 8; ++i) boff[i] = (i * 64 + sr) * 512 + schunk;
  const int lA = (wave << 3) << 6;
  int lB[8];
#pragma unroll
  for (int i = 0; i < 8; ++i) lB[i] = ((i * 64 + (wave << 3))) << 6;

  f32x4 acc[4][4];
#pragma unroll
  for (int m = 0; m < 4; ++m)
#pragma unroll
    for (int n = 0; n < 4; ++n) {
      acc[m][n][0] = 0.f; acc[m][n][1] = 0.f;
      acc[m][n][2] = 0.f; acc[m][n][3] = 0.f;
    }

  for (int t = 0; t < 8; ++t) {
    const int k0 = t << 6;
    gload16(ao + aoff + k0, As + lA);
#pragma unroll
    for (int i = 0; i < 8; ++i) gload16(woT + boff[i] + k0, Bs + lB[i]);
    __syncthreads();

#pragma unroll
    for (int kk = 0; kk < 64; kk += 32) {
      const int kb = kk + ((lane >> 4) << 3);
      bf16x8 af[4], bfr[4];
#pragma unroll
      for (int m = 0; m < 4; ++m) {
        const int R = (m << 4) + (lane & 15);          // rows 0..63
        af[m] = *(const bf16x8*)&As[((R << 6) + kb) ^ ((R & 7) << 3)];
      }
#pragma unroll
      for (int n = 0; n < 4; ++n) {
        const int Cc = (wave << 6) + (n << 4) + (lane & 15);  // 0..511
        bfr[n] = *(const bf16x8*)&Bs[((Cc << 6) + kb) ^ ((Cc & 7) << 3)];
      }
#pragma unroll
      for (int m = 0; m < 4; ++m)
#pragma unroll
        for (int n = 0; n < 4; ++n)
          acc[m][n] = __builtin_amdgcn_mfma_f32_16x16x32_bf16(af[m], bfr[n],
                                                              acc[m][n], 0, 0, 0);
    }
    __syncthreads();   // WAR for next stage; after t==7: fences the C overwrite
  }

  // epilogue 1: C = acc + bias -> Bs as bf16 [64][512], chunk-XOR swizzle
  u16* C = Bs;
  {
    const int lcol = lane & 15;
    const int lrow = (lane >> 4) << 2;
#pragma unroll
    for (int n = 0; n < 4; ++n) {
      const int col = (wave << 6) + (n << 4) + lcol;
      const float bv = bo[col];
#pragma unroll
      for (int m = 0; m < 4; ++m) {
#pragma unroll
        for (int j = 0; j < 4; ++j) {
          const int row = (m << 4) + lrow + j;
          C[((row << 9) + col) ^ ((row & 7) << 3)] = f2b(acc[m][n][j] + bv);
        }
      }
    }
  }
  __syncthreads();

  // epilogue 2: residual + LN, wave-per-row (8 rows per wave)
  const int ebase = lane << 3;
#pragma unroll
  for (int rr = 0; rr < 8; ++rr) {
    const int row = (rr << 3) + wave;
    uint4 cv = *(const uint4*)&C[((row << 9) + ebase) ^ ((row & 7) << 3)];
    const long grow = (long)(m0 + row) * 512;
    uint4 hv4 = *(const uint4*)(hb + grow + ebase);
    const u32 ha[4] = {hv4.x, hv4.y, hv4.z, hv4.w};
    const u32 oa[4] = {cv.x, cv.y, cv.z, cv.w};
    float y[8];
#pragma unroll
    for (int e = 0; e < 4; ++e) {
      y[2 * e]     = b2f((u16)ha[e])         + b2f((u16)oa[e]);
      y[2 * e + 1] = b2f((u16)(ha[e] >> 16)) + b2f((u16)(oa[e] >> 16));
    }
    float s = 0.f, ss = 0.f;
#pragma unroll
    for (int i = 0; i < 8; ++i) { s += y[i]; ss += y[i] * y[i]; }
#pragma unroll
    for (int off = 32; off > 0; off >>= 1) {
      s += __shfl_down(s, off);
      ss += __shfl_down(ss, off);
    }
    s = __shfl(s, 0);
    ss = __shfl(ss, 0);
    const float mean = s * (1.f / 512.f);
    const float var = ss * (1.f / 512.f) - mean * mean;
    const float rinv = rsqrtf(var + 1e-5f);
    float4 g0 = *(const float4*)(gam + ebase);
    float4 g1 = *(const float4*)(gam + ebase + 4);
    float4 b0 = *(const float4*)(bet + ebase);
    float4 b1 = *(const float4*)(bet + ebase + 4);
    float r[8];
    r[0] = (y[0] - mean) * rinv * g0.x + b0.x;
    r[1] = (y[1] - mean) * rinv * g0.y + b0.y;
    r[2] = (y[2] - mean) * rinv * g0.z + b0.z;
    r[3] = (y[3] - mean) * rinv * g0.w + b0.w;
    r[4] = (y[4] - mean) * rinv * g1.x + b1.x;
    r[5] = (y[5] - mean) * rinv * g1.y + b1.y;
    r[6] = (y[6] - mean) * rinv * g1.z + b1.z;
    r[7] = (y[7] - mean) * rinv * g1.w + b1.w;
    uint4 hv;
    hv.x = (u32)f2b(r[0]) | ((u32)f2b(r[1]) << 16);
    hv.y = (u32)f2b(r[2]) | ((u32)f2b(r[3]) << 16);
    hv.z = (u32)f2b(r[4]) | ((u32)f2b(r[5]) << 16);
    hv.w = (u32)f2b(r[6]) | ((u32)f2b(r[7]) << 16);
    *(uint4*)(hb + grow + ebase) = hv;
  }
}

// ---------------- residual + LayerNorm standalone (layer 5) -----------------
__global__ __launch_bounds__(256) void ln_kernel(u16* hb,
                                                 const u16* __restrict__ o,
                                                 const float* __restrict__ g,
                                                 const float* __restrict__ bta,
                                                 float* fout) {
  const int lane = threadIdx.x & 63;
  const int wave = threadIdx.x >> 6;
  const long row = (long)blockIdx.x * 4 + wave;
  u16* hr = hb + row * 512;
  const u16* orow = o + row * 512;
  const int base = lane << 3;
  uint4 hv4 = *(const uint4*)(hr + base);
  uint4 ov = *(const uint4*)(orow + base);
  const u32 ha[4] = {hv4.x, hv4.y, hv4.z, hv4.w};
  const u32 oa[4] = {ov.x, ov.y, ov.z, ov.w};
  float y[8];
#pragma unroll
  for (int e = 0; e < 4; ++e) {
    y[2 * e]     = b2f((u16)ha[e])         + b2f((u16)oa[e]);
    y[2 * e + 1] = b2f((u16)(ha[e] >> 16)) + b2f((u16)(oa[e] >> 16));
  }
  float s = 0.f, ss = 0.f;
#pragma unroll
  for (int i = 0; i < 8; ++i) { s += y[i]; ss += y[i] * y[i]; }
#pragma unroll
  for (int off = 32; off > 0; off >>= 1) {
    s += __shfl_down(s, off);
    ss += __shfl_down(ss, off);
  }
  s = __shfl(s, 0);
  ss = __shfl(ss, 0);
  const float mean = s * (1.f / 512.f);
  const float var = ss * (1.f / 512.f) - mean * mean;
  const float rinv = rsqrtf(var + 1e-5f);
  float4 g0 = *(const float4*)(g + base);
  float4 g1 = *(const float4*)(g + base + 4);
  float4 b0 = *(const float4*)(bta + base);
  float4 b1 = *(const float4*)(bta + base + 4);
  float r[8];
  r[0] = (y[0] - mean) * rinv * g0.x + b0.x;
  r[1] = (y[1] - mean) * rinv * g0.y + b0.y;
  r[2] = (y[2] - mean) * rinv * g0.z + b0.z;
  r[3] = (y[3] - mean) * rinv * g0.w + b0.w;
  r[4] = (y[4] - mean) * rinv * g1.x + b1.x;
  r[5] = (y[5] - mean) * rinv * g1.y + b1.y;
  r[6] = (y[6] - mean) * rinv * g1.z + b1.z;
  r[7] = (y[7] - mean) * rinv * g1.w + b1.w;
  uint4 hv;
  hv.x = (u32)f2b(r[0]) | ((u32)f2b(r[1]) << 16);
  hv.y = (u32)f2b(r[2]) | ((u32)f2b(r[3]) << 16);
  hv.z = (u32)f2b(r[4]) | ((u32)f2b(r[5]) << 16);
  hv.w = (u32)f2b(r[6]) | ((u32)f2b(r[7]) << 16);
  *(uint4*)(hr + base) = hv;
  if (fout) {
    float* fr = fout + row * 512 + base;
    float4 w0 = {r[0], r[1], r[2], r[3]};
    float4 w1 = {r[4], r[5], r[6], r[7]};
    *(float4*)(fr) = w0;
    *(float4*)(fr + 4) = w1;
  }
}

// ---------------- host launcher ----------------
// d_in: x, We, be, cls, Wk, bk, Wv, bv, Wq, bq, Wo, bo, ln_g, ln_b
// ws (100 MiB): hb@0, kb@25M(=xb alias), vb@50M, qb@75M
// d_out doubles as bf16 weight scratch; layer 5 runs the UNFUSED o-proj+ln
// path so no kernel both reads scratch and writes d_out.
extern "C" void kernel_launch(void* const* d_in, const int* in_sizes, int n_in,
                              void* d_out, int out_size, void* d_ws, size_t ws_size,
                              hipStream_t stream) {
  const float* x   = (const float*)d_in[0];
  const float* We  = (const float*)d_in[1];
  const float* be  = (const float*)d_in[2];
  const float* cls = (const float*)d_in[3];
  const float* Wk  = (const float*)d_in[4];
  const float* bk  = (const float*)d_in[5];
  const float* Wv  = (const float*)d_in[6];
  const float* bv  = (const float*)d_in[7];
  const float* Wq  = (const float*)d_in[8];
  const float* bq  = (const float*)d_in[9];
  const float* Wo  = (const float*)d_in[10];
  const float* bo  = (const float*)d_in[11];
  const float* lng = (const float*)d_in[12];
  const float* lnb = (const float*)d_in[13];
  float* out = (float*)d_out;

  char* ws = (char*)d_ws;
  u16* hb = (u16*)ws;
  u16* kb = (u16*)(ws + 26214400);
  u16* vb = (u16*)(ws + 52428800);
  u16* qb = (u16*)(ws + 78643200);
  u16* xb = kb;  // alias: consumed by embed GEMM before K written

  // weight scratch in d_out (bf16 view)
  u16* scr = (u16*)d_out;
  u16* weT = scr + 7340032;
  u16* wqT = scr;                    // 6,553,600
  u16* wkT = scr + 6553600;          // 262,144
  u16* wvT = scr + 6815744;          // 262,144
  u16* woT = scr + 7077888;          // 262,144

  // prologue: cast x; cls rows; convert We^T; embed GEMM -> hb
  cast_kernel<<<1536, 256, 0, stream>>>(x, xb, 393216);
  cls_kernel<<<512, 256, 0, stream>>>(cls, hb);
  convT_kernel<<<dim3(1, 8, 24), 256, 0, stream>>>(We, weT, 64, 512, 32768, 32768);
  gemm_plain<<<dim3(8, 4, 24), 256, 0, stream>>>(
      xb, 1536, 64, weT, 32768, be, 512, hb + 512, 12800, 512, 64);

  for (int l = 0; l < 6; ++l) {
    convT4_kernel<<<dim3(8, 8, 28), 256, 0, stream>>>(
        Wq + (long)l * 6553600, Wk + (long)l * 262144,
        Wv + (long)l * 262144, Wo + (long)l * 262144,
        wqT, wkT, wvT, woT);
    gemm_qkv<<<2400, 256, 0, stream>>>(
        hb, wqT, wkT, wvT,
        bq + (long)l * 12800, bk + (long)l * 512, bv + (long)l * 512,
        qb, kb, vb);
    attn_kernel<<<2048, 256, 0, stream>>>(qb, kb, vb);
    if (l < 5) {
      gemm_oln<<<400, 512, 0, stream>>>(
          kb, woT, bo + (long)l * 512, hb,
          lng + (long)l * 512, lnb + (long)l * 512);
    } else {
      // layer 5: unfused (gemm_oln would read woT scratch in d_out while
      // writing d_out -> cross-block race, round-9 NaN)
      gemm_plain<<<dim3(200, 4, 1), 256, 0, stream>>>(
          kb, 512, 0, woT, 0, bo + (long)l * 512, 0, qb, 512, 0, 512);
      ln_kernel<<<6400, 256, 0, stream>>>(hb, qb, lng + l * 512, lnb + l * 512, out);
    }
  }
}